// Round 6
// baseline (336.241 us; speedup 1.0000x reference)
//
#include <hip/hip_runtime.h>
#include <hip/hip_bf16.h>
#include <math.h>

constexpr int NB   = 4;
constexpr int LL   = 8192;
constexpr int DD   = 256;
constexpr int NH   = 8;
constexpr int HDIM = 32;
constexpr int WNN  = 9;
constexpr int PPAD = 4;

constexpr int CW  = 32;         // windows per attention block
constexpr int RSN = CW + 8;     // 40 staged rows
constexpr int SST = 260;        // bf16 LDS row stride (dword stride 130 ≡ 2 mod 32)
constexpr int PST = 260;        // pos row stride (shorts), full 256-wide rows

typedef __attribute__((ext_vector_type(8))) short bf16x8;
typedef __attribute__((ext_vector_type(4))) float f32x4;

__device__ inline short f2bf(float f) {
  __hip_bfloat16 h = __float2bfloat16(f);
  short s; __builtin_memcpy(&s, &h, 2); return s;
}
__device__ inline float bf2f(short s) {
  unsigned u = ((unsigned)(unsigned short)s) << 16;
  float f; __builtin_memcpy(&f, &u, 4); return f;
}

// ---------------- x -> bf16 (round-3 known-good) ----------------
__global__ __launch_bounds__(256) void conv_x(const float* __restrict__ x, short* __restrict__ XB) {
  size_t i = ((size_t)blockIdx.x * 256 + threadIdx.x) * 4;
  float4 v = *(const float4*)(x + i);
  short4 o; o.x = f2bf(v.x); o.y = f2bf(v.y); o.z = f2bf(v.z); o.w = f2bf(v.w);
  *(short4*)(XB + i) = o;
}

// ---------------- weights (round-3 known-good) ----------------
__global__ __launch_bounds__(256) void prep_w(
    const float* __restrict__ Wq, const float* __restrict__ Wk, const float* __restrict__ Wv,
    const float* __restrict__ Wo, const float* __restrict__ Wout,
    short* __restrict__ WqT, short* __restrict__ WkT, short* __restrict__ WvT,
    short* __restrict__ WoT, short* __restrict__ WoutB) {
  const int t = threadIdx.x, b = blockIdx.x;
  if (b < 4) {
    const float* W = (b == 0) ? Wq : (b == 1) ? Wk : (b == 2) ? Wv : Wo;
    short* T = (b == 0) ? WqT : (b == 1) ? WkT : (b == 2) ? WvT : WoT;
    for (int k = 0; k < 256; k += 4) {
      short4 o;
      o.x = f2bf(W[(size_t)(k + 0) * 256 + t]);
      o.y = f2bf(W[(size_t)(k + 1) * 256 + t]);
      o.z = f2bf(W[(size_t)(k + 2) * 256 + t]);
      o.w = f2bf(W[(size_t)(k + 3) * 256 + t]);
      *(short4*)&T[(size_t)t * 256 + k] = o;
    }
  } else {
    for (int i = t; i < 16384; i += 256) {
      float4 v = *(const float4*)(Wout + (size_t)i * 4);
      short4 o; o.x = f2bf(v.x); o.y = f2bf(v.y); o.z = f2bf(v.z); o.w = f2bf(v.w);
      *(short4*)(WoutB + (size_t)i * 4) = o;
    }
  }
}

// ---------------- pos projection (round-3 known-good) ----------------
__global__ __launch_bounds__(256) void pos_proj(
    const float* __restrict__ pos,
    const float* __restrict__ Wq, const float* __restrict__ Wk, const float* __restrict__ Wv,
    short* __restrict__ PQb, short* __restrict__ PKb, short* __restrict__ PVb) {
  __shared__ float ps[256];
  const int t = threadIdx.x, wrow = blockIdx.x, wh = blockIdx.y;
  const float* W = (wh == 0) ? Wq : (wh == 1) ? Wk : Wv;
  short* P = (wh == 0) ? PQb : (wh == 1) ? PKb : PVb;
  ps[t] = pos[wrow * 256 + t];
  __syncthreads();
  float a = 0.f;
  for (int d = 0; d < 256; ++d) a += ps[d] * W[(size_t)d * 256 + t];
  P[wrow * 256 + t] = f2bf(a);
}

// ---------------- QKV projection via MFMA (round-3 known-good) ----------------
__global__ __launch_bounds__(256) void qkv_mfma(
    const short* __restrict__ XB,
    const short* __restrict__ WT0, const short* __restrict__ WT1, const short* __restrict__ WT2,
    short* __restrict__ O0, short* __restrict__ O1, short* __restrict__ O2) {
  const int t = threadIdx.x, w = t >> 6, lane = t & 63, q = lane >> 4, m = lane & 15;
  const size_t row0 = (size_t)blockIdx.x * 64;
  const short* WT = (blockIdx.y == 0) ? WT0 : (blockIdx.y == 1) ? WT1 : WT2;
  short* O = (blockIdx.y == 0) ? O0 : (blockIdx.y == 1) ? O1 : O2;

  f32x4 acc[4][4];
#pragma unroll
  for (int i = 0; i < 4; ++i)
#pragma unroll
    for (int j = 0; j < 4; ++j) acc[i][j] = (f32x4){0.f, 0.f, 0.f, 0.f};

  const short* abase = XB + (row0 + m) * (size_t)256 + q * 8;
  const short* bbase = WT + (size_t)(w * 64 + m) * 256 + q * 8;
  bf16x8 a[4], b[4];
#pragma unroll
  for (int i = 0; i < 4; ++i) a[i] = *(const bf16x8*)(abase + (size_t)i * 4096);
#pragma unroll
  for (int j = 0; j < 4; ++j) b[j] = *(const bf16x8*)(bbase + (size_t)j * 4096);
#pragma unroll
  for (int kk = 0; kk < 8; ++kk) {
    bf16x8 an[4], bn[4];
    if (kk < 7) {
#pragma unroll
      for (int i = 0; i < 4; ++i) an[i] = *(const bf16x8*)(abase + (size_t)i * 4096 + (kk + 1) * 32);
#pragma unroll
      for (int j = 0; j < 4; ++j) bn[j] = *(const bf16x8*)(bbase + (size_t)j * 4096 + (kk + 1) * 32);
    }
#pragma unroll
    for (int i = 0; i < 4; ++i)
#pragma unroll
      for (int j = 0; j < 4; ++j)
        acc[i][j] = __builtin_amdgcn_mfma_f32_16x16x32_bf16(a[i], b[j], acc[i][j], 0, 0, 0);
    if (kk < 7) {
#pragma unroll
      for (int i = 0; i < 4; ++i) a[i] = an[i];
#pragma unroll
      for (int j = 0; j < 4; ++j) b[j] = bn[j];
    }
  }
#pragma unroll
  for (int i = 0; i < 4; ++i)
#pragma unroll
    for (int j = 0; j < 4; ++j)
#pragma unroll
      for (int r = 0; r < 4; ++r) {
        size_t row = row0 + i * 16 + q * 4 + r;
        int col = w * 64 + j * 16 + m;
        O[row * 256 + col] = f2bf(acc[i][j][r]);
      }
}

// ---------------- windowed attention v3 (hardened): factored banded-dot tables ----------------
// score[n][q][k] = D[n+q][k-q+8] + E[n+q][k] + F[q][n+k] + G[q][k]
// HARDENED vs round 5: Dt fully initialized (zeros out-of-band) AND phase B
// loads only the 9 in-band entries — no uninitialized LDS is ever read.
__global__ __launch_bounds__(256) void attn_kernel(
    const short* __restrict__ XQb, const short* __restrict__ XKb, const short* __restrict__ XVb,
    const short* __restrict__ PQb, const short* __restrict__ PKb, const short* __restrict__ PVb,
    short* __restrict__ CTXB) {
  __shared__ short skv[RSN * SST];        // K rows in phase A, V rows in phase B
  __shared__ short pq[WNN * PST];
  __shared__ short pk[WNN * PST];
  __shared__ short pv[WNN * PST];
  __shared__ float Dt[NH * RSN * 18];     // [h][row][dd 0..16] fp32
  __shared__ short Et[NH * RSN * 10];     // [h][row][k]        bf16
  __shared__ short Ft[NH * 10 * RSN];     // [h][q][row]        bf16
  __shared__ float Gt[NH * WNN * 12];     // [h][q][k]

  const int t = threadIdx.x;
  const int nblk = LL / CW;
  const int b = blockIdx.x / nblk;
  const int n0 = (blockIdx.x % nblk) * CW;
  const size_t base = (size_t)b * LL * DD;

  // stage K rows
#pragma unroll
  for (int i = 0; i < RSN * 64 / 256; ++i) {
    int idx = t + i * 256;
    int r = idx >> 6, c4 = (idx & 63) * 4;
    int j = n0 - PPAD + r;
    short4 v = {0, 0, 0, 0};
    if (j >= 0 && j < LL) v = *(const short4*)(XKb + base + (size_t)j * DD + c4);
    *(short4*)&skv[r * SST + c4] = v;
  }
  // stage pos rows
#pragma unroll
  for (int i = 0; i < 3; ++i) {
    int idx = t + i * 256;
    if (idx < WNN * 64) {
      int r = idx >> 6, c4 = (idx & 63) * 4;
      *(short4*)&pq[r * PST + c4] = *(const short4*)(PQb + r * DD + c4);
      *(short4*)&pk[r * PST + c4] = *(const short4*)(PKb + r * DD + c4);
      *(short4*)&pv[r * PST + c4] = *(const short4*)(PVb + r * DD + c4);
    }
  }
  __syncthreads();

  // ---- phase A: D/E/F tables, unit = (row, head) ----
  for (int u = t; u < RSN * NH; u += 256) {
    const int r = u >> 3, h = u & 7;
    const int hoff = h * HDIM;
    float xqf[32];
    {
      int j = n0 - PPAD + r;
      if (j >= 0 && j < LL) {
        const short* p = XQb + base + (size_t)j * DD + hoff;
#pragma unroll
        for (int c = 0; c < 8; ++c) {
          short4 v = *(const short4*)(p + c * 4);
          xqf[c * 4 + 0] = bf2f(v.x); xqf[c * 4 + 1] = bf2f(v.y);
          xqf[c * 4 + 2] = bf2f(v.z); xqf[c * 4 + 3] = bf2f(v.w);
        }
      } else {
#pragma unroll
        for (int i = 0; i < 32; ++i) xqf[i] = 0.f;
      }
    }
    // banded D — write ALL 17 entries (zeros out-of-band)
    for (int dd = 0; dd < 17; ++dd) {
      int jr = r + dd - 8;
      float acc = 0.f;
      if (jr >= 0 && jr < RSN) {
        const short* kp = &skv[jr * SST + hoff];
#pragma unroll
        for (int c = 0; c < 8; ++c) {
          short4 kv = *(const short4*)(kp + c * 4);
          acc += xqf[c * 4] * bf2f(kv.x) + xqf[c * 4 + 1] * bf2f(kv.y) +
                 xqf[c * 4 + 2] * bf2f(kv.z) + xqf[c * 4 + 3] * bf2f(kv.w);
        }
      }
      Dt[h * (RSN * 18) + r * 18 + dd] = acc;
    }
    // E[r][k] = xq_r . pk_k
#pragma unroll
    for (int k = 0; k < WNN; ++k) {
      const short* kp = &pk[k * PST + hoff];
      float acc = 0.f;
#pragma unroll
      for (int c = 0; c < 8; ++c) {
        short4 kv = *(const short4*)(kp + c * 4);
        acc += xqf[c * 4] * bf2f(kv.x) + xqf[c * 4 + 1] * bf2f(kv.y) +
               xqf[c * 4 + 2] * bf2f(kv.z) + xqf[c * 4 + 3] * bf2f(kv.w);
      }
      Et[h * (RSN * 10) + r * 10 + k] = f2bf(acc);
    }
    // F[q][r] = pq_q . xk_r
    float xkf[32];
    {
      const short* p = &skv[r * SST + hoff];
#pragma unroll
      for (int c = 0; c < 8; ++c) {
        short4 v = *(const short4*)(p + c * 4);
        xkf[c * 4 + 0] = bf2f(v.x); xkf[c * 4 + 1] = bf2f(v.y);
        xkf[c * 4 + 2] = bf2f(v.z); xkf[c * 4 + 3] = bf2f(v.w);
      }
    }
#pragma unroll
    for (int qq = 0; qq < WNN; ++qq) {
      const short* qp = &pq[qq * PST + hoff];
      float acc = 0.f;
#pragma unroll
      for (int c = 0; c < 8; ++c) {
        short4 qv = *(const short4*)(qp + c * 4);
        acc += xkf[c * 4] * bf2f(qv.x) + xkf[c * 4 + 1] * bf2f(qv.y) +
               xkf[c * 4 + 2] * bf2f(qv.z) + xkf[c * 4 + 3] * bf2f(qv.w);
      }
      Ft[h * (10 * RSN) + qq * RSN + r] = f2bf(acc);
    }
  }
  // G[h][q][k] = pq_q . pk_k
  for (int u = t; u < NH * WNN * WNN; u += 256) {
    int h = u / 81, rem = u % 81, qq = rem / 9, k = rem % 9;
    const short* qp = &pq[qq * PST + h * HDIM];
    const short* kp = &pk[k * PST + h * HDIM];
    float acc = 0.f;
#pragma unroll
    for (int c = 0; c < 8; ++c) {
      short4 qv = *(const short4*)(qp + c * 4);
      short4 kv = *(const short4*)(kp + c * 4);
      acc += bf2f(qv.x) * bf2f(kv.x) + bf2f(qv.y) * bf2f(kv.y) +
             bf2f(qv.z) * bf2f(kv.z) + bf2f(qv.w) * bf2f(kv.w);
    }
    Gt[h * 108 + qq * 12 + k] = acc;
  }
  __syncthreads();

  // restage V rows into skv (K no longer needed)
#pragma unroll
  for (int i = 0; i < RSN * 64 / 256; ++i) {
    int idx = t + i * 256;
    int r = idx >> 6, c4 = (idx & 63) * 4;
    int j = n0 - PPAD + r;
    short4 v = {0, 0, 0, 0};
    if (j >= 0 && j < LL) v = *(const short4*)(XVb + base + (size_t)j * DD + c4);
    *(short4*)&skv[r * SST + c4] = v;
  }
  __syncthreads();

  // ---- phase B: thread = (window, head) ----
  const int n = t >> 3, h = t & 7, hoff = h * HDIM;
  float cs[WNN];
#pragma unroll
  for (int k = 0; k < WNN; ++k) cs[k] = 0.f;
  const float scale = 0.17677669529663687f;  // 1/sqrt(32)
#pragma unroll
  for (int q = 0; q < WNN; ++q) {
    const int lr = n + q;
    const float* Dp = &Dt[h * (RSN * 18) + lr * 18];
    const short* Ep = &Et[h * (RSN * 10) + lr * 10];
    const short* Fp = &Ft[h * (10 * RSN) + q * RSN + n];
    const float* Gp = &Gt[h * 108 + q * 12];
    float s_[9]; float mx = -1e30f;
#pragma unroll
    for (int k = 0; k < 9; ++k) {
      // only in-band D entries are read: index 8+k-q ∈ [0,16], row n+k always staged
      s_[k] = Dp[8 + k - q] + bf2f(Ep[k]) + bf2f(Fp[k]) + Gp[k];
      mx = fmaxf(mx, s_[k]);
    }
    float e_[9], sum = 0.f;
#pragma unroll
    for (int k = 0; k < 9; ++k) { e_[k] = __expf((s_[k] - mx) * scale); sum += e_[k]; }
    float inv = 1.f / sum;
#pragma unroll
    for (int k = 0; k < 9; ++k) cs[k] += e_[k] * inv;
  }
  // ctx = sum_k cs[k] * (v[n+k] + pv[k])
#pragma unroll
  for (int c = 0; c < 8; ++c) {
    float o0 = 0.f, o1 = 0.f, o2 = 0.f, o3 = 0.f;
#pragma unroll
    for (int ki = 0; ki < WNN; ++ki) {
      short4 xv4 = *(const short4*)&skv[(n + ki) * SST + hoff + c * 4];
      short4 pv4 = *(const short4*)&pv[ki * PST + hoff + c * 4];
      float wt = cs[ki];
      o0 += wt * (bf2f(xv4.x) + bf2f(pv4.x));
      o1 += wt * (bf2f(xv4.y) + bf2f(pv4.y));
      o2 += wt * (bf2f(xv4.z) + bf2f(pv4.z));
      o3 += wt * (bf2f(xv4.w) + bf2f(pv4.w));
    }
    short4 os; os.x = f2bf(o0); os.y = f2bf(o1); os.z = f2bf(o2); os.w = f2bf(o3);
    *(short4*)(CTXB + base + (size_t)(n0 + n) * DD + hoff + c * 4) = os;
  }
}

// ---------------- fused out stage via MFMA (round-3 known-good) ----------------
__global__ __launch_bounds__(256) void out_mfma(
    const short* __restrict__ CTXB, const float* __restrict__ X,
    const short* __restrict__ WoT, const short* __restrict__ WoutB,
    const float* __restrict__ bo,
    const float* __restrict__ g1, const float* __restrict__ b1,
    const float* __restrict__ g2, const float* __restrict__ b2,
    float* __restrict__ out) {
  __shared__ short ar[64 * 264];
  __shared__ float ws1[64][4], ws2[64][4];
  __shared__ float msh[64], rsh[64];
  __shared__ float g1s[256], b1s[256], g2s[256], b2s[256], bos[256];
  const int t = threadIdx.x, w = t >> 6, lane = t & 63, q = lane >> 4, m = lane & 15;
  const size_t row0 = (size_t)blockIdx.x * 64;
  g1s[t] = g1[t]; b1s[t] = b1[t]; g2s[t] = g2[t]; b2s[t] = b2[t]; bos[t] = bo[t];

  f32x4 acc[4][4];
#pragma unroll
  for (int i = 0; i < 4; ++i)
#pragma unroll
    for (int j = 0; j < 4; ++j) acc[i][j] = (f32x4){0.f, 0.f, 0.f, 0.f};

  const short* abase = CTXB + (row0 + m) * (size_t)256 + q * 8;
  const short* bbase = WoT + (size_t)(w * 64 + m) * 256 + q * 8;
  {
    bf16x8 a[4], b[4];
#pragma unroll
    for (int i = 0; i < 4; ++i) a[i] = *(const bf16x8*)(abase + (size_t)i * 4096);
#pragma unroll
    for (int j = 0; j < 4; ++j) b[j] = *(const bf16x8*)(bbase + (size_t)j * 4096);
#pragma unroll
    for (int kk = 0; kk < 8; ++kk) {
      bf16x8 an[4], bn[4];
      if (kk < 7) {
#pragma unroll
        for (int i = 0; i < 4; ++i) an[i] = *(const bf16x8*)(abase + (size_t)i * 4096 + (kk + 1) * 32);
#pragma unroll
        for (int j = 0; j < 4; ++j) bn[j] = *(const bf16x8*)(bbase + (size_t)j * 4096 + (kk + 1) * 32);
      }
#pragma unroll
      for (int i = 0; i < 4; ++i)
#pragma unroll
        for (int j = 0; j < 4; ++j)
          acc[i][j] = __builtin_amdgcn_mfma_f32_16x16x32_bf16(a[i], b[j], acc[i][j], 0, 0, 0);
      if (kk < 7) {
#pragma unroll
        for (int i = 0; i < 4; ++i) a[i] = an[i];
#pragma unroll
        for (int j = 0; j < 4; ++j) b[j] = bn[j];
      }
    }
  }

  float s1v[4][4], s2v[4][4];
#pragma unroll
  for (int i = 0; i < 4; ++i)
#pragma unroll
    for (int r = 0; r < 4; ++r) {
      float a0 = 0.f, b0 = 0.f;
#pragma unroll
      for (int j = 0; j < 4; ++j) {
        float v = acc[i][j][r] + X[(row0 + i * 16 + q * 4 + r) * 256 + w * 64 + j * 16 + m];
        acc[i][j][r] = v; a0 += v; b0 += v * v;
      }
      s1v[i][r] = a0; s2v[i][r] = b0;
    }
#pragma unroll
  for (int i = 0; i < 4; ++i)
#pragma unroll
    for (int r = 0; r < 4; ++r)
#pragma unroll
      for (int msk = 1; msk < 16; msk <<= 1) {
        s1v[i][r] += __shfl_xor(s1v[i][r], msk, 64);
        s2v[i][r] += __shfl_xor(s2v[i][r], msk, 64);
      }
  if (m == 0) {
#pragma unroll
    for (int i = 0; i < 4; ++i)
#pragma unroll
      for (int r = 0; r < 4; ++r) {
        ws1[i * 16 + q * 4 + r][w] = s1v[i][r];
        ws2[i * 16 + q * 4 + r][w] = s2v[i][r];
      }
  }
  __syncthreads();
  if (t < 64) {
    float a0 = 0.f, b0 = 0.f;
#pragma unroll
    for (int ww = 0; ww < 4; ++ww) { a0 += ws1[t][ww]; b0 += ws2[t][ww]; }
    float mean = a0 * (1.f / 256.f);
    float var = b0 * (1.f / 256.f) - mean * mean;
    msh[t] = mean; rsh[t] = rsqrtf(var + 1e-5f);
  }
  __syncthreads();

#pragma unroll
  for (int i = 0; i < 4; ++i)
#pragma unroll
    for (int r = 0; r < 4; ++r) {
      int row = i * 16 + q * 4 + r;
      float mean = msh[row], rst = rsh[row];
#pragma unroll
      for (int j = 0; j < 4; ++j) {
        int col = w * 64 + j * 16 + m;
        float v = (acc[i][j][r] - mean) * rst * g1s[col] + b1s[col];
        ar[row * 264 + col] = f2bf(v);
      }
    }
  __syncthreads();

#pragma unroll
  for (int i = 0; i < 4; ++i)
#pragma unroll
    for (int j = 0; j < 4; ++j) acc[i][j] = (f32x4){0.f, 0.f, 0.f, 0.f};
  const short* b2base = WoutB + (size_t)(w * 64 + m) * 256 + q * 8;
  {
    bf16x8 b[4];
#pragma unroll
    for (int j = 0; j < 4; ++j) b[j] = *(const bf16x8*)(b2base + (size_t)j * 4096);
#pragma unroll
    for (int kk = 0; kk < 8; ++kk) {
      bf16x8 bn[4];
      if (kk < 7) {
#pragma unroll
        for (int j = 0; j < 4; ++j) bn[j] = *(const bf16x8*)(b2base + (size_t)j * 4096 + (kk + 1) * 32);
      }
      bf16x8 a[4];
#pragma unroll
      for (int i = 0; i < 4; ++i) a[i] = *(const bf16x8*)&ar[(i * 16 + m) * 264 + kk * 32 + q * 8];
#pragma unroll
      for (int i = 0; i < 4; ++i)
#pragma unroll
        for (int j = 0; j < 4; ++j)
          acc[i][j] = __builtin_amdgcn_mfma_f32_16x16x32_bf16(a[i], b[j], acc[i][j], 0, 0, 0);
      if (kk < 7) {
#pragma unroll
        for (int j = 0; j < 4; ++j) b[j] = bn[j];
      }
    }
  }

#pragma unroll
  for (int i = 0; i < 4; ++i)
#pragma unroll
    for (int r = 0; r < 4; ++r) {
      int row = i * 16 + q * 4 + r;
      float a0 = 0.f, b0 = 0.f;
#pragma unroll
      for (int j = 0; j < 4; ++j) {
        int col = w * 64 + j * 16 + m;
        float v = acc[i][j][r] + bos[col] + bf2f(ar[row * 264 + col]);
        acc[i][j][r] = v; a0 += v; b0 += v * v;
      }
      s1v[i][r] = a0; s2v[i][r] = b0;
    }
#pragma unroll
  for (int i = 0; i < 4; ++i)
#pragma unroll
    for (int r = 0; r < 4; ++r)
#pragma unroll
      for (int msk = 1; msk < 16; msk <<= 1) {
        s1v[i][r] += __shfl_xor(s1v[i][r], msk, 64);
        s2v[i][r] += __shfl_xor(s2v[i][r], msk, 64);
      }
  if (m == 0) {
#pragma unroll
    for (int i = 0; i < 4; ++i)
#pragma unroll
      for (int r = 0; r < 4; ++r) {
        ws1[i * 16 + q * 4 + r][w] = s1v[i][r];
        ws2[i * 16 + q * 4 + r][w] = s2v[i][r];
      }
  }
  __syncthreads();
  if (t < 64) {
    float a0 = 0.f, b0 = 0.f;
#pragma unroll
    for (int ww = 0; ww < 4; ++ww) { a0 += ws1[t][ww]; b0 += ws2[t][ww]; }
    float mean = a0 * (1.f / 256.f);
    float var = b0 * (1.f / 256.f) - mean * mean;
    msh[t] = mean; rsh[t] = rsqrtf(var + 1e-5f);
  }
  __syncthreads();

#pragma unroll
  for (int i = 0; i < 4; ++i)
#pragma unroll
    for (int r = 0; r < 4; ++r) {
      int row = i * 16 + q * 4 + r;
      float mean = msh[row], rst = rsh[row];
#pragma unroll
      for (int j = 0; j < 4; ++j) {
        int col = w * 64 + j * 16 + m;
        float v = (acc[i][j][r] - mean) * rst * g2s[col] + b2s[col];
        out[(row0 + row) * 256 + col] = fmaxf(v, 0.f);
      }
    }
}

extern "C" void kernel_launch(void* const* d_in, const int* in_sizes, int n_in,
                              void* d_out, int out_size, void* d_ws, size_t ws_size,
                              hipStream_t stream) {
  const float* x    = (const float*)d_in[0];
  const float* Wq   = (const float*)d_in[1];
  const float* Wk   = (const float*)d_in[2];
  const float* Wv   = (const float*)d_in[3];
  const float* Wo   = (const float*)d_in[4];
  const float* pos  = (const float*)d_in[5];
  const float* Wout = (const float*)d_in[6];
  const float* bo   = (const float*)d_in[7];
  const float* g1   = (const float*)d_in[8];
  const float* b1   = (const float*)d_in[9];
  const float* g2   = (const float*)d_in[10];
  const float* b2   = (const float*)d_in[11];
  float* out = (float*)d_out;

  const size_t nel = (size_t)NB * LL * DD;
  char* wsb = (char*)d_ws;
  short* XB   = (short*)wsb; wsb += nel * 2;
  short* XQb  = (short*)wsb; wsb += nel * 2;
  short* XKb  = (short*)wsb; wsb += nel * 2;
  short* XVb  = (short*)wsb; wsb += nel * 2;
  short* CTXB = (short*)wsb; wsb += nel * 2;
  short* WqT   = (short*)wsb; wsb += 65536 * 2;
  short* WkT   = (short*)wsb; wsb += 65536 * 2;
  short* WvT   = (short*)wsb; wsb += 65536 * 2;
  short* WoT   = (short*)wsb; wsb += 65536 * 2;
  short* WoutB = (short*)wsb; wsb += 65536 * 2;
  short* PQb = (short*)wsb; wsb += WNN * DD * 2;
  short* PKb = (short*)wsb; wsb += WNN * DD * 2;
  short* PVb = (short*)wsb; wsb += WNN * DD * 2;

  conv_x<<<(unsigned)(nel / 4 / 256), 256, 0, stream>>>(x, XB);
  prep_w<<<5, 256, 0, stream>>>(Wq, Wk, Wv, Wo, Wout, WqT, WkT, WvT, WoT, WoutB);
  pos_proj<<<dim3(WNN, 3), 256, 0, stream>>>(pos, Wq, Wk, Wv, PQb, PKb, PVb);
  qkv_mfma<<<dim3((unsigned)(NB * LL / 64), 3), 256, 0, stream>>>(XB, WqT, WkT, WvT, XQb, XKb, XVb);
  attn_kernel<<<NB * (LL / CW), 256, 0, stream>>>(XQb, XKb, XVb, PQb, PKb, PVb, CTXB);
  out_mfma<<<(unsigned)(NB * LL / 64), 256, 0, stream>>>(CTXB, x, WoT, WoutB, bo, g1, b1, g2, b2, out);
}

// Round 7
// 273.074 us; speedup vs baseline: 1.2313x; 1.2313x over previous
//
#include <hip/hip_runtime.h>
#include <hip/hip_bf16.h>
#include <math.h>

constexpr int NB   = 4;
constexpr int LL   = 8192;
constexpr int DD   = 256;
constexpr int NH   = 8;
constexpr int HDIM = 32;
constexpr int WNN  = 9;
constexpr int PPAD = 4;

constexpr int CW  = 32;         // windows per attention block
constexpr int RSN = CW + 8;     // 40 staged rows
constexpr int SST = 260;        // bf16 LDS row stride (dword stride 130 ≡ 2 mod 32)

typedef __attribute__((ext_vector_type(8))) short bf16x8;
typedef __attribute__((ext_vector_type(4))) float f32x4;

__device__ inline short f2bf(float f) {
  __hip_bfloat16 h = __float2bfloat16(f);
  short s; __builtin_memcpy(&s, &h, 2); return s;
}
__device__ inline float bf2f(short s) {
  unsigned u = ((unsigned)(unsigned short)s) << 16;
  float f; __builtin_memcpy(&f, &u, 4); return f;
}

// ---------------- prep: weight transposes + Wout conv + pos projection, one dispatch ----------------
__global__ __launch_bounds__(256) void prep_all(
    const float* __restrict__ Wq, const float* __restrict__ Wk, const float* __restrict__ Wv,
    const float* __restrict__ Wo, const float* __restrict__ Wout, const float* __restrict__ pos,
    short* __restrict__ WqT, short* __restrict__ WkT, short* __restrict__ WvT,
    short* __restrict__ WoT, short* __restrict__ WoutB,
    short* __restrict__ PQb, short* __restrict__ PKb, short* __restrict__ PVb) {
  __shared__ float sm[64 * 65];
  const int t = threadIdx.x, b = blockIdx.x;
  if (b < 64) {
    // 64x64 tile transpose: T[n][k] = bf16(W[k][n])
    const int wi = b >> 4, tile = b & 15;
    const int r0 = (tile >> 2) * 64, c0 = (tile & 3) * 64;
    const float* W = (wi == 0) ? Wq : (wi == 1) ? Wk : (wi == 2) ? Wv : Wo;
    short* T = (wi == 0) ? WqT : (wi == 1) ? WkT : (wi == 2) ? WvT : WoT;
    const int tr = t >> 6, tc = t & 63;
#pragma unroll
    for (int i = 0; i < 16; ++i) {
      int r = tr + i * 4;
      sm[r * 65 + tc] = W[(size_t)(r0 + r) * 256 + c0 + tc];
    }
    __syncthreads();
#pragma unroll
    for (int i = 0; i < 16; ++i) {
      int cj = tr + i * 4;
      T[(size_t)(c0 + cj) * 256 + r0 + tc] = f2bf(sm[tc * 65 + cj]);
    }
  } else if (b < 68) {
    const int idx = b - 64;
    for (int i = t; i < 4096; i += 256) {
      float4 v = *(const float4*)(Wout + ((size_t)idx * 4096 + i) * 4);
      short4 o; o.x = f2bf(v.x); o.y = f2bf(v.y); o.z = f2bf(v.z); o.w = f2bf(v.w);
      *(short4*)(WoutB + ((size_t)idx * 4096 + i) * 4) = o;
    }
  } else {
    const int wh = b - 68;
    const float* W = (wh == 0) ? Wq : (wh == 1) ? Wk : Wv;
    short* P = (wh == 0) ? PQb : (wh == 1) ? PKb : PVb;
    for (int i = t; i < WNN * 256; i += 256) sm[i] = pos[i];
    __syncthreads();
    float a[WNN];
#pragma unroll
    for (int w = 0; w < WNN; ++w) a[w] = 0.f;
    for (int d = 0; d < 256; ++d) {
      float wv = W[(size_t)d * 256 + t];
#pragma unroll
      for (int w = 0; w < WNN; ++w) a[w] += sm[w * 256 + d] * wv;  // LDS broadcast
    }
#pragma unroll
    for (int w = 0; w < WNN; ++w) P[w * 256 + t] = f2bf(a[w]);
  }
}

// ---------------- fused conv + QKV projection: one block = 32 rows, all 3 outputs ----------------
__global__ __launch_bounds__(256) void qkv_fused(
    const float* __restrict__ x,
    const short* __restrict__ WT0, const short* __restrict__ WT1, const short* __restrict__ WT2,
    short* __restrict__ O0, short* __restrict__ O1, short* __restrict__ O2) {
  __shared__ short xs[32 * 264];   // 528B row stride: 16B-aligned, 2-way banks for A-frags
  const int t = threadIdx.x, w = t >> 6, lane = t & 63, q = lane >> 4, m = lane & 15;
  const size_t row0 = (size_t)blockIdx.x * 32;

  // stage x fp32 -> bf16 LDS (x is read exactly once device-wide)
#pragma unroll
  for (int i = 0; i < 8; ++i) {
    int idx = t + i * 256;
    int r = idx >> 6, c4 = (idx & 63) * 4;
    float4 v = *(const float4*)(x + (row0 + r) * 256 + c4);
    short4 o; o.x = f2bf(v.x); o.y = f2bf(v.y); o.z = f2bf(v.z); o.w = f2bf(v.w);
    *(short4*)&xs[r * 264 + c4] = o;
  }
  __syncthreads();

  f32x4 acc[3][2][4];  // [buf][Mtile][Ntile]; wave w owns cols w*64..w*64+63 of each buf
#pragma unroll
  for (int bu = 0; bu < 3; ++bu)
#pragma unroll
    for (int i = 0; i < 2; ++i)
#pragma unroll
      for (int j = 0; j < 4; ++j) acc[bu][i][j] = (f32x4){0.f, 0.f, 0.f, 0.f};

#pragma unroll
  for (int kk = 0; kk < 8; ++kk) {
    bf16x8 a[2];
#pragma unroll
    for (int i = 0; i < 2; ++i) a[i] = *(const bf16x8*)&xs[(i * 16 + m) * 264 + kk * 32 + q * 8];
#pragma unroll
    for (int bu = 0; bu < 3; ++bu) {
      const short* WT = (bu == 0) ? WT0 : (bu == 1) ? WT1 : WT2;
#pragma unroll
      for (int j = 0; j < 4; ++j) {
        bf16x8 bb = *(const bf16x8*)(WT + (size_t)(w * 64 + j * 16 + m) * 256 + kk * 32 + q * 8);
#pragma unroll
        for (int i = 0; i < 2; ++i)
          acc[bu][i][j] = __builtin_amdgcn_mfma_f32_16x16x32_bf16(a[i], bb, acc[bu][i][j], 0, 0, 0);
      }
    }
  }
#pragma unroll
  for (int bu = 0; bu < 3; ++bu) {
    short* O = (bu == 0) ? O0 : (bu == 1) ? O1 : O2;
#pragma unroll
    for (int i = 0; i < 2; ++i)
#pragma unroll
      for (int j = 0; j < 4; ++j)
#pragma unroll
        for (int r = 0; r < 4; ++r)
          O[(row0 + i * 16 + q * 4 + r) * 256 + w * 64 + j * 16 + m] = f2bf(acc[bu][i][j][r]);
  }
}

// ---------------- windowed attention v2 (round-3 known-good): thread = (window, head) ----------------
__global__ __launch_bounds__(256, 2) void attn_kernel(
    const short* __restrict__ XQb, const short* __restrict__ XKb, const short* __restrict__ XVb,
    const short* __restrict__ PQb, const short* __restrict__ PKb, const short* __restrict__ PVb,
    short* __restrict__ CTXB) {
  __shared__ short sq[RSN * SST];
  __shared__ short sk[RSN * SST];
  __shared__ short sv[RSN * SST];
  __shared__ short pq[WNN * SST];
  __shared__ short pk[WNN * SST];
  __shared__ short pv[WNN * SST];

  const int t = threadIdx.x;
  const int nblk = LL / CW;
  const int b = blockIdx.x / nblk;
  const int n0 = (blockIdx.x % nblk) * CW;
  const size_t base = (size_t)b * LL * DD;

#pragma unroll
  for (int i = 0; i < RSN * 64 / 256; ++i) {   // 10
    int idx = t + i * 256;
    int r = idx >> 6, c4 = (idx & 63) * 4;
    int j = n0 - PPAD + r;
    short4 vq = {0, 0, 0, 0}, vk = vq, vv = vq;
    if (j >= 0 && j < LL) {
      size_t off = base + (size_t)j * DD + c4;
      vq = *(const short4*)(XQb + off);
      vk = *(const short4*)(XKb + off);
      vv = *(const short4*)(XVb + off);
    }
    *(short4*)&sq[r * SST + c4] = vq;
    *(short4*)&sk[r * SST + c4] = vk;
    *(short4*)&sv[r * SST + c4] = vv;
  }
#pragma unroll
  for (int i = 0; i < 3; ++i) {
    int idx = t + i * 256;
    if (idx < WNN * 64) {
      int r = idx >> 6, c4 = (idx & 63) * 4;
      *(short4*)&pq[r * SST + c4] = *(const short4*)(PQb + r * DD + c4);
      *(short4*)&pk[r * SST + c4] = *(const short4*)(PKb + r * DD + c4);
      *(short4*)&pv[r * SST + c4] = *(const short4*)(PVb + r * DD + c4);
    }
  }
  __syncthreads();

  const int n = t >> 3;        // window within block
  const int h = t & 7;         // head
  const int hoff = h * HDIM;

  float sc[WNN][WNN];
#pragma unroll
  for (int qi = 0; qi < WNN; ++qi)
#pragma unroll
    for (int ki = 0; ki < WNN; ++ki) sc[qi][ki] = 0.f;

#pragma unroll
  for (int c = 0; c < 8; ++c) {
    float qv[WNN][4], kv[WNN][4];
#pragma unroll
    for (int r = 0; r < WNN; ++r) {
      short4 xa = *(const short4*)&sq[(n + r) * SST + hoff + c * 4];
      short4 pa = *(const short4*)&pq[r * SST + hoff + c * 4];
      qv[r][0] = bf2f(xa.x) + bf2f(pa.x);
      qv[r][1] = bf2f(xa.y) + bf2f(pa.y);
      qv[r][2] = bf2f(xa.z) + bf2f(pa.z);
      qv[r][3] = bf2f(xa.w) + bf2f(pa.w);
      short4 xb = *(const short4*)&sk[(n + r) * SST + hoff + c * 4];
      short4 pb = *(const short4*)&pk[r * SST + hoff + c * 4];
      kv[r][0] = bf2f(xb.x) + bf2f(pb.x);
      kv[r][1] = bf2f(xb.y) + bf2f(pb.y);
      kv[r][2] = bf2f(xb.z) + bf2f(pb.z);
      kv[r][3] = bf2f(xb.w) + bf2f(pb.w);
    }
#pragma unroll
    for (int qi = 0; qi < WNN; ++qi)
#pragma unroll
      for (int ki = 0; ki < WNN; ++ki)
        sc[qi][ki] += qv[qi][0] * kv[ki][0] + qv[qi][1] * kv[ki][1] +
                      qv[qi][2] * kv[ki][2] + qv[qi][3] * kv[ki][3];
  }

  float cs[WNN];
#pragma unroll
  for (int ki = 0; ki < WNN; ++ki) cs[ki] = 0.f;
  const float scale = 0.17677669529663687f;  // 1/sqrt(32)
#pragma unroll
  for (int qi = 0; qi < WNN; ++qi) {
    float mx = sc[qi][0];
#pragma unroll
    for (int ki = 1; ki < WNN; ++ki) mx = fmaxf(mx, sc[qi][ki]);
    float sum = 0.f;
    float e[WNN];
#pragma unroll
    for (int ki = 0; ki < WNN; ++ki) { e[ki] = __expf((sc[qi][ki] - mx) * scale); sum += e[ki]; }
    float inv = 1.f / sum;
#pragma unroll
    for (int ki = 0; ki < WNN; ++ki) cs[ki] += e[ki] * inv;
  }

#pragma unroll
  for (int c = 0; c < 8; ++c) {
    float o0 = 0.f, o1 = 0.f, o2 = 0.f, o3 = 0.f;
#pragma unroll
    for (int ki = 0; ki < WNN; ++ki) {
      short4 xv4 = *(const short4*)&sv[(n + ki) * SST + hoff + c * 4];
      short4 pv4 = *(const short4*)&pv[ki * SST + hoff + c * 4];
      float wt = cs[ki];
      o0 += wt * (bf2f(xv4.x) + bf2f(pv4.x));
      o1 += wt * (bf2f(xv4.y) + bf2f(pv4.y));
      o2 += wt * (bf2f(xv4.z) + bf2f(pv4.z));
      o3 += wt * (bf2f(xv4.w) + bf2f(pv4.w));
    }
    short4 os; os.x = f2bf(o0); os.y = f2bf(o1); os.z = f2bf(o2); os.w = f2bf(o3);
    *(short4*)(CTXB + base + (size_t)(n0 + n) * DD + hoff + c * 4) = os;
  }
}

// ---------------- fused out stage via MFMA (round-3 known-good) ----------------
__global__ __launch_bounds__(256) void out_mfma(
    const short* __restrict__ CTXB, const float* __restrict__ X,
    const short* __restrict__ WoT, const short* __restrict__ WoutB,
    const float* __restrict__ bo,
    const float* __restrict__ g1, const float* __restrict__ b1,
    const float* __restrict__ g2, const float* __restrict__ b2,
    float* __restrict__ out) {
  __shared__ short ar[64 * 264];
  __shared__ float ws1[64][4], ws2[64][4];
  __shared__ float msh[64], rsh[64];
  __shared__ float g1s[256], b1s[256], g2s[256], b2s[256], bos[256];
  const int t = threadIdx.x, w = t >> 6, lane = t & 63, q = lane >> 4, m = lane & 15;
  const size_t row0 = (size_t)blockIdx.x * 64;
  g1s[t] = g1[t]; b1s[t] = b1[t]; g2s[t] = g2[t]; b2s[t] = b2[t]; bos[t] = bo[t];

  f32x4 acc[4][4];
#pragma unroll
  for (int i = 0; i < 4; ++i)
#pragma unroll
    for (int j = 0; j < 4; ++j) acc[i][j] = (f32x4){0.f, 0.f, 0.f, 0.f};

  const short* abase = CTXB + (row0 + m) * (size_t)256 + q * 8;
  const short* bbase = WoT + (size_t)(w * 64 + m) * 256 + q * 8;
  {
    bf16x8 a[4], b[4];
#pragma unroll
    for (int i = 0; i < 4; ++i) a[i] = *(const bf16x8*)(abase + (size_t)i * 4096);
#pragma unroll
    for (int j = 0; j < 4; ++j) b[j] = *(const bf16x8*)(bbase + (size_t)j * 4096);
#pragma unroll
    for (int kk = 0; kk < 8; ++kk) {
      bf16x8 an[4], bn[4];
      if (kk < 7) {
#pragma unroll
        for (int i = 0; i < 4; ++i) an[i] = *(const bf16x8*)(abase + (size_t)i * 4096 + (kk + 1) * 32);
#pragma unroll
        for (int j = 0; j < 4; ++j) bn[j] = *(const bf16x8*)(bbase + (size_t)j * 4096 + (kk + 1) * 32);
      }
#pragma unroll
      for (int i = 0; i < 4; ++i)
#pragma unroll
        for (int j = 0; j < 4; ++j)
          acc[i][j] = __builtin_amdgcn_mfma_f32_16x16x32_bf16(a[i], b[j], acc[i][j], 0, 0, 0);
      if (kk < 7) {
#pragma unroll
        for (int i = 0; i < 4; ++i) a[i] = an[i];
#pragma unroll
        for (int j = 0; j < 4; ++j) b[j] = bn[j];
      }
    }
  }

  float s1v[4][4], s2v[4][4];
#pragma unroll
  for (int i = 0; i < 4; ++i)
#pragma unroll
    for (int r = 0; r < 4; ++r) {
      float a0 = 0.f, b0 = 0.f;
#pragma unroll
      for (int j = 0; j < 4; ++j) {
        float v = acc[i][j][r] + X[(row0 + i * 16 + q * 4 + r) * 256 + w * 64 + j * 16 + m];
        acc[i][j][r] = v; a0 += v; b0 += v * v;
      }
      s1v[i][r] = a0; s2v[i][r] = b0;
    }
#pragma unroll
  for (int i = 0; i < 4; ++i)
#pragma unroll
    for (int r = 0; r < 4; ++r)
#pragma unroll
      for (int msk = 1; msk < 16; msk <<= 1) {
        s1v[i][r] += __shfl_xor(s1v[i][r], msk, 64);
        s2v[i][r] += __shfl_xor(s2v[i][r], msk, 64);
      }
  if (m == 0) {
#pragma unroll
    for (int i = 0; i < 4; ++i)
#pragma unroll
      for (int r = 0; r < 4; ++r) {
        ws1[i * 16 + q * 4 + r][w] = s1v[i][r];
        ws2[i * 16 + q * 4 + r][w] = s2v[i][r];
      }
  }
  __syncthreads();
  if (t < 64) {
    float a0 = 0.f, b0 = 0.f;
#pragma unroll
    for (int ww = 0; ww < 4; ++ww) { a0 += ws1[t][ww]; b0 += ws2[t][ww]; }
    float mean = a0 * (1.f / 256.f);
    float var = b0 * (1.f / 256.f) - mean * mean;
    msh[t] = mean; rsh[t] = rsqrtf(var + 1e-5f);
  }
  __syncthreads();

#pragma unroll
  for (int i = 0; i < 4; ++i)
#pragma unroll
    for (int r = 0; r < 4; ++r) {
      int row = i * 16 + q * 4 + r;
      float mean = msh[row], rst = rsh[row];
#pragma unroll
      for (int j = 0; j < 4; ++j) {
        int col = w * 64 + j * 16 + m;
        float v = (acc[i][j][r] - mean) * rst * g1s[col] + b1s[col];
        ar[row * 264 + col] = f2bf(v);
      }
    }
  __syncthreads();

#pragma unroll
  for (int i = 0; i < 4; ++i)
#pragma unroll
    for (int j = 0; j < 4; ++j) acc[i][j] = (f32x4){0.f, 0.f, 0.f, 0.f};
  const short* b2base = WoutB + (size_t)(w * 64 + m) * 256 + q * 8;
  {
    bf16x8 b[4];
#pragma unroll
    for (int j = 0; j < 4; ++j) b[j] = *(const bf16x8*)(b2base + (size_t)j * 4096);
#pragma unroll
    for (int kk = 0; kk < 8; ++kk) {
      bf16x8 bn[4];
      if (kk < 7) {
#pragma unroll
        for (int j = 0; j < 4; ++j) bn[j] = *(const bf16x8*)(b2base + (size_t)j * 4096 + (kk + 1) * 32);
      }
      bf16x8 a[4];
#pragma unroll
      for (int i = 0; i < 4; ++i) a[i] = *(const bf16x8*)&ar[(i * 16 + m) * 264 + kk * 32 + q * 8];
#pragma unroll
      for (int i = 0; i < 4; ++i)
#pragma unroll
        for (int j = 0; j < 4; ++j)
          acc[i][j] = __builtin_amdgcn_mfma_f32_16x16x32_bf16(a[i], b[j], acc[i][j], 0, 0, 0);
      if (kk < 7) {
#pragma unroll
        for (int j = 0; j < 4; ++j) b[j] = bn[j];
      }
    }
  }

#pragma unroll
  for (int i = 0; i < 4; ++i)
#pragma unroll
    for (int r = 0; r < 4; ++r) {
      int row = i * 16 + q * 4 + r;
      float a0 = 0.f, b0 = 0.f;
#pragma unroll
      for (int j = 0; j < 4; ++j) {
        int col = w * 64 + j * 16 + m;
        float v = acc[i][j][r] + bos[col] + bf2f(ar[row * 264 + col]);
        acc[i][j][r] = v; a0 += v; b0 += v * v;
      }
      s1v[i][r] = a0; s2v[i][r] = b0;
    }
#pragma unroll
  for (int i = 0; i < 4; ++i)
#pragma unroll
    for (int r = 0; r < 4; ++r)
#pragma unroll
      for (int msk = 1; msk < 16; msk <<= 1) {
        s1v[i][r] += __shfl_xor(s1v[i][r], msk, 64);
        s2v[i][r] += __shfl_xor(s2v[i][r], msk, 64);
      }
  if (m == 0) {
#pragma unroll
    for (int i = 0; i < 4; ++i)
#pragma unroll
      for (int r = 0; r < 4; ++r) {
        ws1[i * 16 + q * 4 + r][w] = s1v[i][r];
        ws2[i * 16 + q * 4 + r][w] = s2v[i][r];
      }
  }
  __syncthreads();
  if (t < 64) {
    float a0 = 0.f, b0 = 0.f;
#pragma unroll
    for (int ww = 0; ww < 4; ++ww) { a0 += ws1[t][ww]; b0 += ws2[t][ww]; }
    float mean = a0 * (1.f / 256.f);
    float var = b0 * (1.f / 256.f) - mean * mean;
    msh[t] = mean; rsh[t] = rsqrtf(var + 1e-5f);
  }
  __syncthreads();

#pragma unroll
  for (int i = 0; i < 4; ++i)
#pragma unroll
    for (int r = 0; r < 4; ++r) {
      int row = i * 16 + q * 4 + r;
      float mean = msh[row], rst = rsh[row];
#pragma unroll
      for (int j = 0; j < 4; ++j) {
        int col = w * 64 + j * 16 + m;
        float v = (acc[i][j][r] - mean) * rst * g2s[col] + b2s[col];
        out[(row0 + row) * 256 + col] = fmaxf(v, 0.f);
      }
    }
}

extern "C" void kernel_launch(void* const* d_in, const int* in_sizes, int n_in,
                              void* d_out, int out_size, void* d_ws, size_t ws_size,
                              hipStream_t stream) {
  const float* x    = (const float*)d_in[0];
  const float* Wq   = (const float*)d_in[1];
  const float* Wk   = (const float*)d_in[2];
  const float* Wv   = (const float*)d_in[3];
  const float* Wo   = (const float*)d_in[4];
  const float* pos  = (const float*)d_in[5];
  const float* Wout = (const float*)d_in[6];
  const float* bo   = (const float*)d_in[7];
  const float* g1   = (const float*)d_in[8];
  const float* b1   = (const float*)d_in[9];
  const float* g2   = (const float*)d_in[10];
  const float* b2   = (const float*)d_in[11];
  float* out = (float*)d_out;

  const size_t nel = (size_t)NB * LL * DD;
  char* wsb = (char*)d_ws;
  short* XQb  = (short*)wsb; wsb += nel * 2;
  short* XKb  = (short*)wsb; wsb += nel * 2;
  short* XVb  = (short*)wsb; wsb += nel * 2;
  short* CTXB = (short*)wsb; wsb += nel * 2;
  short* WqT   = (short*)wsb; wsb += 65536 * 2;
  short* WkT   = (short*)wsb; wsb += 65536 * 2;
  short* WvT   = (short*)wsb; wsb += 65536 * 2;
  short* WoT   = (short*)wsb; wsb += 65536 * 2;
  short* WoutB = (short*)wsb; wsb += 65536 * 2;
  short* PQb = (short*)wsb; wsb += WNN * DD * 2;
  short* PKb = (short*)wsb; wsb += WNN * DD * 2;
  short* PVb = (short*)wsb; wsb += WNN * DD * 2;

  prep_all<<<71, 256, 0, stream>>>(Wq, Wk, Wv, Wo, Wout, pos,
                                   WqT, WkT, WvT, WoT, WoutB, PQb, PKb, PVb);
  qkv_fused<<<(unsigned)(NB * LL / 32), 256, 0, stream>>>(x, WqT, WkT, WvT, XQb, XKb, XVb);
  attn_kernel<<<NB * (LL / CW), 256, 0, stream>>>(XQb, XKb, XVb, PQb, PKb, PVb, CTXB);
  out_mfma<<<(unsigned)(NB * LL / 64), 256, 0, stream>>>(CTXB, x, WoT, WoutB, bo, g1, b1, g2, b2, out);
}